// Round 14
// baseline (122.863 us; speedup 1.0000x reference)
//
#include <hip/hip_runtime.h>
#include <math.h>

// ---------------- workspace layout (bytes) ----------------
#define O_RPD    (0)                  // row_ptr dst-CSR (~200KB)
#define O_DINV   (512*1024)           // N floats
#define O_SMALL  (768*1024)           // few KB
#define O_GHD    (1792*1024)          // NB*256 ints [bucket][chunk]
#define O_GOD    (2304*1024)
#define O_BSD    (2816*1024)          // NB+1 ints
#define O_PART   (3072*1024)          // 1024*132*4 = 540KB
#define O_XS     (3712*1024)          // N float4 = 800KB
#define O_G1     (4608*1024)          // N float4 = 800KB (agg1 scaled, dinv)
#define O_SRTD   (5632*1024)          // E uints = 3.2MB
#define O_COLD   (12544*1024)         // E ints = 3.2MB
// small[]: [0..127] w2qk  [128] bias  [132..259] S  [260] R  [264..391] newT

#define NCHUNK 256
#define ZBLOCKS 1024

static __device__ __forceinline__ int blockExclScan256(int v, volatile int* lds, int t) {
    int lane = t & 63, wid = t >> 6;
    int incl = v;
#pragma unroll
    for (int off = 1; off < 64; off <<= 1) {
        int n = __shfl_up(incl, off);
        if (lane >= off) incl += n;
    }
    if (lane == 63) lds[wid] = incl;
    __syncthreads();
    if (t == 0) {
        int s = 0;
#pragma unroll
        for (int i = 0; i < 4; ++i) { int x = lds[i]; lds[i] = s; s += x; }
    }
    __syncthreads();
    return lds[wid] + incl - v;
}

// ---------------- A1: per-chunk dst-bucket histogram; spare block: tiny1 ----------------
__global__ void k_hist(const int* __restrict__ eidx, int* __restrict__ ghD,
                       const float* __restrict__ trainOT, const float* __restrict__ Wq,
                       const float* __restrict__ bq, const float* __restrict__ Wk,
                       const float* __restrict__ bk, const float* __restrict__ W2,
                       const float* __restrict__ b2, float* __restrict__ small,
                       int E, int CS, int NB) {
    int b = blockIdx.x, t = threadIdx.x;
    if (b == NCHUNK) {
        // ---- tiny1: w2qk & bias ----
        __shared__ float kv[64];
        __shared__ float wqk[128];
        __shared__ float fred[256];
        if (t < 64) {
            float acc = bk[t];
            for (int j = 0; j < 128; ++j) acc += trainOT[j] * Wk[j * 64 + t];
            kv[t] = acc;
        }
        __syncthreads();
        if (t < 128) {
            float aq = 0.f;
            for (int c2 = 0; c2 < 64; ++c2) aq += Wq[t * 64 + c2] * kv[c2];
            wqk[t] = aq;
        }
        fred[t] = (t < 64) ? bq[t] * kv[t] : 0.f;
        __syncthreads();
        for (int off = 128; off >= 1; off >>= 1) { if (t < off) fred[t] += fred[t + off]; __syncthreads(); }
        float bqs = fred[0];
        __syncthreads();
        if (t < 128) {
            float a2 = 0.f;
            for (int j = 0; j < 128; ++j) a2 += W2[t * 128 + j] * wqk[j];
            small[t] = a2;
        }
        fred[t] = (t < 128) ? b2[t] * wqk[t] : 0.f;
        __syncthreads();
        for (int off = 128; off >= 1; off >>= 1) { if (t < off) fred[t] += fred[t + off]; __syncthreads(); }
        if (t == 0) small[128] = bqs + fred[0];
        return;
    }
    __shared__ int lh[256];
    const int* dst = eidx + E;
    lh[t] = 0; __syncthreads();
    int s = b * CS, e = min(E, s + CS);
    for (int i = s + t; i < e; i += 256) atomicAdd(&lh[dst[i] >> 8], 1);
    __syncthreads();
    if (t < NB) ghD[t * NCHUNK + b] = lh[t];              // transposed: [bucket][chunk]
}

// ---------------- A2: per-bucket base (parallel row-sums) + chunk-offset scan ----------------
__global__ void k_goff(const int* __restrict__ ghD, int* __restrict__ goD,
                       int* __restrict__ bsD, int E, int NB) {
    __shared__ int lred[256];
    __shared__ int lds1[4];
    int nb = blockIdx.x, t = threadIdx.x;
    // base = sum of bucket totals below nb (each thread sums one row, int4 loads, L2-resident)
    int rs = 0;
    if (t < nb) {
        const int4* row = reinterpret_cast<const int4*>(ghD + t * NCHUNK);
        for (int i = 0; i < NCHUNK / 4; ++i) { int4 p = row[i]; rs += p.x + p.y + p.z + p.w; }
    }
    lred[t] = rs; __syncthreads();
    for (int off = 128; off >= 1; off >>= 1) { if (t < off) lred[t] += lred[t + off]; __syncthreads(); }
    int base = lred[0];
    __syncthreads();
    if (t == 0) { bsD[nb] = base; if (nb == NB - 1) bsD[NB] = E; }
    int g = ghD[nb * NCHUNK + t];
    int gx = blockExclScan256(g, lds1, t);
    goD[nb * NCHUNK + t] = base + gx;
}

// ---------------- A3: scatter edges into dst-bucket-sorted runs ----------------
__global__ void k_scatter(const int* __restrict__ eidx, const int* __restrict__ goD,
                          unsigned int* __restrict__ srtD, int E, int CS, int NB) {
    __shared__ int lcur[256];
    int b = blockIdx.x, t = threadIdx.x;
    const int* dst = eidx + E;
    const int* src = eidx;
    if (t < NB) lcur[t] = goD[t * NCHUNK + b];
    __syncthreads();
    int s = b * CS, e = min(E, s + CS);
    for (int i = s + t; i < e; i += 256) {
        int k = dst[i];
        int pos = atomicAdd(&lcur[k >> 8], 1);
        srtD[pos] = ((unsigned int)(k & 255) << 16) | (unsigned int)src[i];  // N <= 65536
    }
}

// ---------------- B: per-bucket degree + row_ptr + CSR fill + dinv/xs4 ----------------
__global__ void k_build(const unsigned int* __restrict__ srtD, const int* __restrict__ bsD,
                        int* __restrict__ rpD, int* __restrict__ colD,
                        float* __restrict__ dinv, const float* __restrict__ x,
                        float4* __restrict__ xs4, int N) {
    __shared__ int lcnt[256];
    __shared__ int lpos[256];
    __shared__ int lds1[4];
    int nb = blockIdx.x, t = threadIdx.x;
    lcnt[t] = 0; __syncthreads();
    int s = bsD[nb], e = bsD[nb + 1];
    for (int i = s + t; i < e; i += 256) atomicAdd(&lcnt[srtD[i] >> 16], 1);
    __syncthreads();
    int c = lcnt[t];
    int cx = blockExclScan256(c, lds1, t);
    int rpv = s + cx;
    int node = (nb << 8) + t;
    rpD[node] = rpv;
    lpos[t] = rpv;
    if (node < N) {
        float d = rsqrtf((float)(c + 1));   // +1 self-loop
        dinv[node] = d;
        float4 v;
        v.x = x[node * 3] * d; v.y = x[node * 3 + 1] * d; v.z = x[node * 3 + 2] * d; v.w = 0.f;
        xs4[node] = v;
    }
    __syncthreads();
    for (int i = s + t; i < e; i += 256) {
        unsigned int v = srtD[i];
        int p = atomicAdd(&lpos[v >> 16], 1);
        colD[p] = (int)(v & 0xffffu);
    }
}

// ---------------- g1: 16 lanes/node 3-dim feature aggregation ----------------
__global__ void k_g1k(const float4* __restrict__ xs4, const int* __restrict__ rpD,
                      const int* __restrict__ colD, const float* __restrict__ dinv,
                      float4* __restrict__ g1, int N) {
    int t = threadIdx.x;
    int sub = t & 15;
    int node = blockIdx.x * 16 + (t >> 4);
    if (node >= N) return;
    float di = dinv[node];
    int s = rpD[node], e = rpD[node + 1];
    float a0 = 0.f, a1 = 0.f, a2 = 0.f;
    for (int j = s + sub; j < e; j += 16) {
        float4 xv = xs4[colD[j]];
        a0 += xv.x; a1 += xv.y; a2 += xv.z;
    }
    if (sub == 0) { float4 xv = xs4[node]; a0 += xv.x; a1 += xv.y; a2 += xv.z; }
#pragma unroll
    for (int off = 1; off < 16; off <<= 1) {
        a0 += __shfl_xor(a0, off);
        a1 += __shfl_xor(a1, off);
        a2 += __shfl_xor(a2, off);
    }
    if (sub == 0) {
        float4 gv; gv.x = a0 * di; gv.y = a1 * di; gv.z = a2 * di; gv.w = di;
        g1[node] = gv;
    }
}

// ---------------- dvz fused: H[n] = hs[n]+sum_{u->n} hs[u] (hs recomputed from g1);
//                  dv = dinv*(H.w2qk); rel = sigmoid((dv+bias)/8); S += rel*dinv*H; R += rel
__global__ void k_dvz(const float4* __restrict__ g1, const int* __restrict__ rpD,
                      const int* __restrict__ colD, const float* __restrict__ W1,
                      const float* __restrict__ b1, const float* __restrict__ small,
                      float* __restrict__ part, int N) {
    __shared__ float W1s[384];
    __shared__ float b1s[128];
    __shared__ float wqs[128];
    __shared__ float sS[4][132];
    int t = threadIdx.x, lane = t & 63, wid = t >> 6;
    int sub = lane & 15;
    if (t < 128) { W1s[t] = W1[t]; W1s[128 + t] = W1[128 + t]; W1s[256 + t] = W1[256 + t];
                   b1s[t] = b1[t]; wqs[t] = small[t]; }
    __syncthreads();
    float bias = small[128];
    float sacc[8];
#pragma unroll
    for (int m = 0; m < 8; ++m) sacc[m] = 0.f;
    float Racc = 0.f;
    for (int node = blockIdx.x * 16 + (t >> 4); node < N; node += ZBLOCKS * 16) {
        float4 gs = g1[node];
        float di = gs.w;
        float H[8];
#pragma unroll
        for (int m = 0; m < 8; ++m) {           // self term
            int c = sub * 8 + m;
            float h = fmaxf(gs.x * W1s[c] + gs.y * W1s[128 + c] + gs.z * W1s[256 + c] + b1s[c], 0.f);
            H[m] = h * di;
        }
        int s = rpD[node], e = rpD[node + 1];
        for (int j = s; j < e; j += 2) {
            int u0 = colD[j];
            float4 ga = g1[u0];
            float4 gb;
            if (j + 1 < e) { gb = g1[colD[j + 1]]; }
            else { gb.x = 0.f; gb.y = 0.f; gb.z = 0.f; gb.w = 0.f; }   // w=0 => no contribution
#pragma unroll
            for (int m = 0; m < 8; ++m) {
                int c = sub * 8 + m;
                float ha = fmaxf(ga.x * W1s[c] + ga.y * W1s[128 + c] + ga.z * W1s[256 + c] + b1s[c], 0.f);
                float hb = fmaxf(gb.x * W1s[c] + gb.y * W1s[128 + c] + gb.z * W1s[256 + c] + b1s[c], 0.f);
                H[m] += ha * ga.w + hb * gb.w;
            }
        }
        float dv = 0.f;
#pragma unroll
        for (int m = 0; m < 8; ++m) dv += H[m] * wqs[sub * 8 + m];
#pragma unroll
        for (int off = 1; off < 16; off <<= 1) dv += __shfl_xor(dv, off);
        float zz = (dv * di + bias) * 0.125f;   // / sqrt(64)
        float rel = 1.f / (1.f + __expf(-zz));
        float relw = rel * di;
#pragma unroll
        for (int m = 0; m < 8; ++m) sacc[m] += relw * H[m];
        if (sub == 0) Racc += rel;
    }
#pragma unroll
    for (int m = 0; m < 8; ++m) {
        sacc[m] += __shfl_xor(sacc[m], 16);
        sacc[m] += __shfl_xor(sacc[m], 32);
    }
    Racc += __shfl_xor(Racc, 16);
    Racc += __shfl_xor(Racc, 32);
    if (lane < 16) {
#pragma unroll
        for (int m = 0; m < 8; ++m) sS[wid][sub * 8 + m] = sacc[m];
    }
    if (lane == 0) sS[wid][128] = Racc;
    __syncthreads();
    if (t < 129) part[blockIdx.x * 132 + t] = sS[0][t] + sS[1][t] + sS[2][t] + sS[3][t];
}

// ---------------- reduce part columns in parallel (129 blocks) ----------------
__global__ void k_reduce_part(const float* __restrict__ part, int nblocks, float* __restrict__ small) {
    int c = blockIdx.x;   // 0..128 (128 == R -> small[260])
    float acc = 0.f;
    for (int b = threadIdx.x; b < nblocks; b += blockDim.x) acc += part[b * 132 + c];
    __shared__ float sd[256];
    sd[threadIdx.x] = acc; __syncthreads();
    for (int off = 128; off; off >>= 1) { if (threadIdx.x < off) sd[threadIdx.x] += sd[threadIdx.x + off]; __syncthreads(); }
    if (threadIdx.x == 0) small[132 + c] = sd[0];
}

// ---------------- parallel tail matvecs: 1024 threads, 8-way K slices ----------------
__global__ void k_tinytail(const float* __restrict__ trainOT, const float* __restrict__ W2,
                           const float* __restrict__ b2, const float* __restrict__ Wv,
                           const float* __restrict__ bv, float* __restrict__ small,
                           float* __restrict__ out_tail) {
    __shared__ float partial[1024];
    __shared__ float Ss[128];
    __shared__ float t1[128];
    int t = threadIdx.x;           // 1024
    int o = t & 127, sl = t >> 7;  // 8 K-slices of 16
    if (t < 128) Ss[t] = small[132 + t];
    __syncthreads();
    float R = small[260];
    float acc = 0.f;
#pragma unroll
    for (int j = sl * 16; j < sl * 16 + 16; ++j) acc += Ss[j] * W2[j * 128 + o];
    partial[t] = acc; __syncthreads();
    if (t < 128) {
        float v = R * b2[t];
#pragma unroll
        for (int k = 0; k < 8; ++k) v += partial[t + 128 * k];
        t1[t] = v;
    }
    __syncthreads();
    float acc2 = 0.f;
#pragma unroll
    for (int j = sl * 16; j < sl * 16 + 16; ++j) acc2 += t1[j] * Wv[j * 128 + o];
    partial[t] = acc2; __syncthreads();
    if (t < 128) {
        float v = R * bv[t];
#pragma unroll
        for (int k = 0; k < 8; ++k) v += partial[t + 128 * k];
        float nt = trainOT[t] + v;
        small[264 + t] = nt;
        out_tail[t] = nt;
    }
}

// ---------------- speak: out[j] = newT @ Ws[:,j] + bs[j], 4 K-slices, LDS reduce ----------
__global__ void k_speak(const float* __restrict__ Ws, const float* __restrict__ bs,
                        const float* __restrict__ small, float* __restrict__ out, int out_n) {
    __shared__ float nt[128];
    __shared__ float s0[256], s1[256];
    int t = threadIdx.x;
    if (t < 128) nt[t] = small[264 + t];
    __syncthreads();
    int jj = (t & 63) * 2, sl = t >> 6;       // 4 K-slices of 32
    int j = blockIdx.x * 128 + jj;
    float a0 = 0.f, a1 = 0.f;
    if (j < out_n) {
        const float* w = Ws + (size_t)(sl * 32) * out_n + j;
        for (int k = 0; k < 32; ++k) {
            float cv = nt[sl * 32 + k];
            float2 r = *reinterpret_cast<const float2*>(w + (size_t)k * out_n);
            a0 += cv * r.x; a1 += cv * r.y;
        }
    }
    s0[t] = a0; s1[t] = a1; __syncthreads();
    if (t < 64 && j < out_n) {
        out[j]     = s0[t] + s0[t + 64] + s0[t + 128] + s0[t + 192] + bs[j];
        out[j + 1] = s1[t] + s1[t + 64] + s1[t + 128] + s1[t + 192] + bs[j + 1];
    }
}

extern "C" void kernel_launch(void* const* d_in, const int* in_sizes, int n_in,
                              void* d_out, int out_size, void* d_ws, size_t ws_size,
                              hipStream_t stream) {
    const float* features = (const float*)d_in[0];
    const int*   eidx     = (const int*)d_in[1];
    const float* trainOT  = (const float*)d_in[2];
    const float* W1 = (const float*)d_in[3];
    const float* b1 = (const float*)d_in[4];
    const float* W2 = (const float*)d_in[5];
    const float* b2 = (const float*)d_in[6];
    const float* Wq = (const float*)d_in[7];
    const float* bq = (const float*)d_in[8];
    const float* Wk = (const float*)d_in[9];
    const float* bk = (const float*)d_in[10];
    const float* Wv = (const float*)d_in[11];
    const float* bv = (const float*)d_in[12];
    const float* Ws = (const float*)d_in[13];
    const float* bs = (const float*)d_in[14];

    int N = in_sizes[0] / 3;
    int E = in_sizes[1] / 2;
    int NB = (N + 255) >> 8;
    int CS = (E + NCHUNK - 1) / NCHUNK;

    char* ws = (char*)d_ws;
    int*   rpD   = (int*)(ws + O_RPD);
    float* dinv  = (float*)(ws + O_DINV);
    float* small = (float*)(ws + O_SMALL);
    int*   ghD   = (int*)(ws + O_GHD);
    int*   goD   = (int*)(ws + O_GOD);
    int*   bsD   = (int*)(ws + O_BSD);
    float* part  = (float*)(ws + O_PART);
    float4* xs4  = (float4*)(ws + O_XS);
    float4* g1   = (float4*)(ws + O_G1);
    unsigned int* srtD = (unsigned int*)(ws + O_SRTD);
    int*   colD  = (int*)(ws + O_COLD);
    float* out   = (float*)d_out;
    int out_n = out_size - 128;

    k_hist<<<NCHUNK + 1, 256, 0, stream>>>(eidx, ghD,
                                           trainOT, Wq, bq, Wk, bk, W2, b2, small, E, CS, NB);
    k_goff<<<NB, 256, 0, stream>>>(ghD, goD, bsD, E, NB);
    k_scatter<<<NCHUNK, 256, 0, stream>>>(eidx, goD, srtD, E, CS, NB);
    k_build<<<NB, 256, 0, stream>>>(srtD, bsD, rpD, colD, dinv, features, xs4, N);
    k_g1k<<<(N + 15) / 16, 256, 0, stream>>>(xs4, rpD, colD, dinv, g1, N);
    k_dvz<<<ZBLOCKS, 256, 0, stream>>>(g1, rpD, colD, W1, b1, small, part, N);
    k_reduce_part<<<129, 256, 0, stream>>>(part, ZBLOCKS, small);
    k_tinytail<<<1, 1024, 0, stream>>>(trainOT, W2, b2, Wv, bv, small, out + out_n);
    k_speak<<<(out_n + 127) / 128, 256, 0, stream>>>(Ws, bs, small, out, out_n);
}

// Round 15
// 98.533 us; speedup vs baseline: 1.2469x; 1.2469x over previous
//
#include <hip/hip_runtime.h>
#include <math.h>

// ---------------- workspace layout (bytes) ----------------
#define O_RPD    (0)                  // row_ptr dst-CSR (~200KB)
#define O_DINV   (512*1024)           // N floats
#define O_SMALL  (768*1024)           // few KB
#define O_Y      (1024*1024)          // N floats
#define O_RELW   (1280*1024)          // N floats
#define O_REL    (1536*1024)          // N floats
#define O_GHD    (1792*1024)          // NB*256 ints [bucket][chunk]
#define O_GHS    (2048*1024)
#define O_GOD    (2304*1024)
#define O_GOS    (2560*1024)
#define O_BSD    (2816*1024)          // NB+1 ints
#define O_BSS    (2944*1024)
#define O_PART   (3072*1024)          // NB*132*4 ~ 103KB
#define O_XS     (3712*1024)          // N float4 = 800KB
#define O_G1     (4608*1024)          // N float4 = 800KB
#define O_SRTD   (5632*1024)          // E uints = 3.2MB
#define O_SRTS   (9216*1024)          // E uints = 3.2MB
#define O_COLD   (12544*1024)         // E ints = 3.2MB
// small[]: [0..127] w2qk  [128] bias  [132..259] S  [260] R  [264..391] newT

#define NCHUNK 256

static __device__ __forceinline__ int blockExclScan256(int v, volatile int* lds, int t) {
    int lane = t & 63, wid = t >> 6;
    int incl = v;
#pragma unroll
    for (int off = 1; off < 64; off <<= 1) {
        int n = __shfl_up(incl, off);
        if (lane >= off) incl += n;
    }
    if (lane == 63) lds[wid] = incl;
    __syncthreads();
    if (t == 0) {
        int s = 0;
#pragma unroll
        for (int i = 0; i < 4; ++i) { int x = lds[i]; lds[i] = s; s += x; }
    }
    __syncthreads();
    return lds[wid] + incl - v;
}

// ---------------- A1: per-chunk bucket histograms (both orientations); spare: tiny1 ----------
__global__ void k_hist(const int* __restrict__ eidx, int* __restrict__ ghD,
                       int* __restrict__ ghS,
                       const float* __restrict__ trainOT, const float* __restrict__ Wq,
                       const float* __restrict__ bq, const float* __restrict__ Wk,
                       const float* __restrict__ bk, const float* __restrict__ W2,
                       const float* __restrict__ b2, float* __restrict__ small,
                       int E, int CS, int NB) {
    int b = blockIdx.x, t = threadIdx.x;
    if (b == NCHUNK) {
        if (blockIdx.y) return;
        // ---- tiny1: w2qk & bias ----
        __shared__ float kv[64];
        __shared__ float wqk[128];
        __shared__ float fred[256];
        if (t < 64) {
            float acc = bk[t];
            for (int j = 0; j < 128; ++j) acc += trainOT[j] * Wk[j * 64 + t];
            kv[t] = acc;
        }
        __syncthreads();
        if (t < 128) {
            float aq = 0.f;
            for (int c2 = 0; c2 < 64; ++c2) aq += Wq[t * 64 + c2] * kv[c2];
            wqk[t] = aq;
        }
        fred[t] = (t < 64) ? bq[t] * kv[t] : 0.f;
        __syncthreads();
        for (int off = 128; off >= 1; off >>= 1) { if (t < off) fred[t] += fred[t + off]; __syncthreads(); }
        float bqs = fred[0];
        __syncthreads();
        if (t < 128) {
            float a2 = 0.f;
            for (int j = 0; j < 128; ++j) a2 += W2[t * 128 + j] * wqk[j];
            small[t] = a2;
        }
        fred[t] = (t < 128) ? b2[t] * wqk[t] : 0.f;
        __syncthreads();
        for (int off = 128; off >= 1; off >>= 1) { if (t < off) fred[t] += fred[t + off]; __syncthreads(); }
        if (t == 0) small[128] = bqs + fred[0];
        return;
    }
    __shared__ int lh[256];
    const int* arr = blockIdx.y ? eidx : (eidx + E);      // y=0: dst, y=1: src
    int* gh = blockIdx.y ? ghS : ghD;
    lh[t] = 0; __syncthreads();
    int s = b * CS, e = min(E, s + CS);
    for (int i = s + t; i < e; i += 256) atomicAdd(&lh[arr[i] >> 8], 1);
    __syncthreads();
    if (t < NB) gh[t * NCHUNK + b] = lh[t];               // transposed: [bucket][chunk]
}

// ---------------- A2: per-bucket base (parallel row-sums) + chunk-offset scan ----------------
__global__ void k_goff(const int* __restrict__ ghD, const int* __restrict__ ghS,
                       int* __restrict__ goD, int* __restrict__ goS,
                       int* __restrict__ bsD, int* __restrict__ bsS, int E, int NB) {
    __shared__ int lred[256];
    __shared__ int lds1[4];
    int nb = blockIdx.x, t = threadIdx.x;
    const int* gh = blockIdx.y ? ghS : ghD;
    int* go = blockIdx.y ? goS : goD;
    int* bs = blockIdx.y ? bsS : bsD;
    // base = sum of bucket totals below nb (thread t sums row t; int4 loads, L2-resident)
    int rs = 0;
    if (t < nb) {
        const int4* row = reinterpret_cast<const int4*>(gh + t * NCHUNK);
        for (int i = 0; i < NCHUNK / 4; ++i) { int4 p = row[i]; rs += p.x + p.y + p.z + p.w; }
    }
    lred[t] = rs; __syncthreads();
    for (int off = 128; off >= 1; off >>= 1) { if (t < off) lred[t] += lred[t + off]; __syncthreads(); }
    int base = lred[0];
    __syncthreads();
    if (t == 0) { bs[nb] = base; if (nb == NB - 1) bs[NB] = E; }
    int g = gh[nb * NCHUNK + t];
    int gx = blockExclScan256(g, lds1, t);
    go[nb * NCHUNK + t] = base + gx;
}

// ---------------- A3: scatter edges into bucket-sorted runs (grid NCHUNK x 2) ----------------
__global__ void k_scatter(const int* __restrict__ eidx, const int* __restrict__ goD,
                          const int* __restrict__ goS, unsigned int* __restrict__ srtD,
                          unsigned int* __restrict__ srtS, int E, int CS, int NB) {
    __shared__ int lcur[256];
    int b = blockIdx.x, t = threadIdx.x;
    const int* key = blockIdx.y ? eidx : (eidx + E);      // y=0: key=dst,val=src; y=1: key=src,val=dst
    const int* val = blockIdx.y ? (eidx + E) : eidx;
    const int* go  = blockIdx.y ? goS : goD;
    unsigned int* srt = blockIdx.y ? srtS : srtD;
    if (t < NB) lcur[t] = go[t * NCHUNK + b];
    __syncthreads();
    int s = b * CS, e = min(E, s + CS);
    for (int i = s + t; i < e; i += 256) {
        int k = key[i];
        int pos = atomicAdd(&lcur[k >> 8], 1);
        srt[pos] = ((unsigned int)(k & 255) << 16) | (unsigned int)val[i];   // N <= 65536
    }
}

// ---------------- B: dst-only per-bucket degree + row_ptr + CSR fill + dinv/xs4 ----------
__global__ void k_build(const unsigned int* __restrict__ srtD, const int* __restrict__ bsD,
                        int* __restrict__ rpD, int* __restrict__ colD,
                        float* __restrict__ dinv, const float* __restrict__ x,
                        float4* __restrict__ xs4, int N) {
    __shared__ int lcnt[256];
    __shared__ int lpos[256];
    __shared__ int lds1[4];
    int nb = blockIdx.x, t = threadIdx.x;
    lcnt[t] = 0; __syncthreads();
    int s = bsD[nb], e = bsD[nb + 1];
    for (int i = s + t; i < e; i += 256) atomicAdd(&lcnt[srtD[i] >> 16], 1);
    __syncthreads();
    int c = lcnt[t];
    int cx = blockExclScan256(c, lds1, t);
    int rpv = s + cx;
    int node = (nb << 8) + t;
    rpD[node] = rpv;
    lpos[t] = rpv;
    if (node < N) {
        float d = rsqrtf((float)(c + 1));   // +1 self-loop
        dinv[node] = d;
        float4 v;
        v.x = x[node * 3] * d; v.y = x[node * 3 + 1] * d; v.z = x[node * 3 + 2] * d; v.w = 0.f;
        xs4[node] = v;
    }
    __syncthreads();
    for (int i = s + t; i < e; i += 256) {
        unsigned int v = srtD[i];
        int p = atomicAdd(&lpos[v >> 16], 1);
        colD[p] = (int)(v & 0xffffu);
    }
}

// ---------------- layer 1: 16 lanes/node; store g1=(agg,di) + y ----------------
__global__ void k_y(const float4* __restrict__ xs4, const int* __restrict__ rpD,
                    const int* __restrict__ colD, const float* __restrict__ dinv,
                    const float* __restrict__ W1, const float* __restrict__ b1,
                    const float* __restrict__ small, float4* __restrict__ g1,
                    float* __restrict__ y, int N) {
    int t = threadIdx.x;
    int sub = t & 15;
    int node = blockIdx.x * 16 + (t >> 4);
    if (node >= N) return;
    float di = dinv[node];
    int s = rpD[node], e = rpD[node + 1];
    float a0 = 0.f, a1 = 0.f, a2 = 0.f;
    for (int j = s + sub; j < e; j += 16) {
        float4 xv = xs4[colD[j]];
        a0 += xv.x; a1 += xv.y; a2 += xv.z;
    }
    if (sub == 0) { float4 xv = xs4[node]; a0 += xv.x; a1 += xv.y; a2 += xv.z; }
#pragma unroll
    for (int off = 1; off < 16; off <<= 1) {
        a0 += __shfl_xor(a0, off);
        a1 += __shfl_xor(a1, off);
        a2 += __shfl_xor(a2, off);
    }
    a0 *= di; a1 *= di; a2 *= di;
    float yl = 0.f;
#pragma unroll
    for (int m = 0; m < 8; ++m) {
        int c = sub * 8 + m;
        float h = fmaxf(a0 * W1[c] + a1 * W1[128 + c] + a2 * W1[256 + c] + b1[c], 0.f);
        yl += h * small[c];
    }
#pragma unroll
    for (int off = 1; off < 16; off <<= 1) yl += __shfl_xor(yl, off);
    if (sub == 0) {
        y[node] = yl * di;
        float4 gv; gv.x = a0; gv.y = a1; gv.z = a2; gv.w = di;
        g1[node] = gv;
    }
}

// ---------------- dv/rel: scalar aggregation of y over dst-CSR ----------------
__global__ void k_dv(const float* __restrict__ y, const int* __restrict__ rpD,
                     const int* __restrict__ colD, const float* __restrict__ dinv,
                     const float* __restrict__ small, float* __restrict__ relw,
                     float* __restrict__ rel, int N) {
    int t = threadIdx.x;
    int sub = t & 15;
    int node = blockIdx.x * 16 + (t >> 4);
    if (node >= N) return;
    float di = dinv[node];
    int s = rpD[node], e = rpD[node + 1];
    float acc = (sub == 0) ? y[node] : 0.f;
    for (int j = s + sub; j < e; j += 16) acc += y[colD[j]];
#pragma unroll
    for (int off = 1; off < 16; off <<= 1) acc += __shfl_xor(acc, off);
    float z = (acc * di + small[128]) * 0.125f;     // / sqrt(64)
    float r = 1.f / (1.f + __expf(-z));
    if (sub == 0) { rel[node] = r; relw[node] = r * di; }
}

// ---------------- zS: per src-bucket — z[u] = relw[u] + sum relw[dst] (LDS atomics over srtS);
//                  then S += z[u]*dinv[u]*relu(g1[u].W1+b1); R += rel[u]. Per-node recompute. ----
__global__ void k_zS(const unsigned int* __restrict__ srtS, const int* __restrict__ bsS,
                     const float* __restrict__ relw, const float* __restrict__ rel,
                     const float4* __restrict__ g1, const float* __restrict__ W1,
                     const float* __restrict__ b1, float* __restrict__ part, int N) {
    __shared__ float zl[256];
    __shared__ float W1s[384];
    __shared__ float b1s[128];
    __shared__ float sS[4][132];
    int nb = blockIdx.x, t = threadIdx.x, lane = t & 63, wid = t >> 6;
    int sub = lane & 15, gid = wid * 4 + (lane >> 4);     // 16 groups of 16 lanes
    int node0 = (nb << 8) + t;
    zl[t] = (node0 < N) ? relw[node0] : 0.f;              // self term
    if (t < 128) { W1s[t] = W1[t]; W1s[128 + t] = W1[128 + t]; W1s[256 + t] = W1[256 + t];
                   b1s[t] = b1[t]; }
    __syncthreads();
    int s = bsS[nb], e = bsS[nb + 1];
    for (int i = s + t; i < e; i += 256) {
        unsigned int v = srtS[i];
        atomicAdd(&zl[v >> 16], relw[v & 0xffffu]);       // z[src] += relw[dst]
    }
    __syncthreads();
    float sacc[8];
#pragma unroll
    for (int m = 0; m < 8; ++m) sacc[m] = 0.f;
    float Racc = 0.f;
#pragma unroll 4
    for (int r = 0; r < 16; ++r) {
        int nl = gid * 16 + r;
        int node = (nb << 8) + nl;
        if (node < N) {
            float4 gv = g1[node];
            float zw = zl[nl] * gv.w;                     // z * dinv
#pragma unroll
            for (int m = 0; m < 8; ++m) {
                int c = sub * 8 + m;
                float h = fmaxf(gv.x * W1s[c] + gv.y * W1s[128 + c] + gv.z * W1s[256 + c] + b1s[c], 0.f);
                sacc[m] += zw * h;
            }
            if (sub == 0) Racc += rel[node];
        }
    }
#pragma unroll
    for (int m = 0; m < 8; ++m) {
        sacc[m] += __shfl_xor(sacc[m], 16);
        sacc[m] += __shfl_xor(sacc[m], 32);
    }
    Racc += __shfl_xor(Racc, 16);
    Racc += __shfl_xor(Racc, 32);
    if (lane < 16) {
#pragma unroll
        for (int m = 0; m < 8; ++m) sS[wid][sub * 8 + m] = sacc[m];
    }
    if (lane == 0) sS[wid][128] = Racc;
    __syncthreads();
    if (t < 129) part[nb * 132 + t] = sS[0][t] + sS[1][t] + sS[2][t] + sS[3][t];
}

// ---------------- reduce part columns in parallel (129 blocks) ----------------
__global__ void k_reduce_part(const float* __restrict__ part, int nblocks, float* __restrict__ small) {
    int c = blockIdx.x;   // 0..128 (128 == R -> small[260])
    float acc = 0.f;
    for (int b = threadIdx.x; b < nblocks; b += blockDim.x) acc += part[b * 132 + c];
    __shared__ float sd[256];
    sd[threadIdx.x] = acc; __syncthreads();
    for (int off = 128; off; off >>= 1) { if (threadIdx.x < off) sd[threadIdx.x] += sd[threadIdx.x + off]; __syncthreads(); }
    if (threadIdx.x == 0) small[132 + c] = sd[0];
}

// ---------------- parallel tail matvecs: 1024 threads, 8-way K slices ----------------
__global__ void k_tinytail(const float* __restrict__ trainOT, const float* __restrict__ W2,
                           const float* __restrict__ b2, const float* __restrict__ Wv,
                           const float* __restrict__ bv, float* __restrict__ small,
                           float* __restrict__ out_tail) {
    __shared__ float partial[1024];
    __shared__ float Ss[128];
    __shared__ float t1[128];
    int t = threadIdx.x;           // 1024
    int o = t & 127, sl = t >> 7;  // 8 K-slices of 16
    if (t < 128) Ss[t] = small[132 + t];
    __syncthreads();
    float R = small[260];
    float acc = 0.f;
#pragma unroll
    for (int j = sl * 16; j < sl * 16 + 16; ++j) acc += Ss[j] * W2[j * 128 + o];
    partial[t] = acc; __syncthreads();
    if (t < 128) {
        float v = R * b2[t];
#pragma unroll
        for (int k = 0; k < 8; ++k) v += partial[t + 128 * k];
        t1[t] = v;
    }
    __syncthreads();
    float acc2 = 0.f;
#pragma unroll
    for (int j = sl * 16; j < sl * 16 + 16; ++j) acc2 += t1[j] * Wv[j * 128 + o];
    partial[t] = acc2; __syncthreads();
    if (t < 128) {
        float v = R * bv[t];
#pragma unroll
        for (int k = 0; k < 8; ++k) v += partial[t + 128 * k];
        float nt = trainOT[t] + v;
        small[264 + t] = nt;
        out_tail[t] = nt;
    }
}

// ---------------- speak: out[j] = newT @ Ws[:,j] + bs[j], 4 K-slices, LDS reduce ----------
__global__ void k_speak(const float* __restrict__ Ws, const float* __restrict__ bs,
                        const float* __restrict__ small, float* __restrict__ out, int out_n) {
    __shared__ float nt[128];
    __shared__ float s0[256], s1[256];
    int t = threadIdx.x;
    if (t < 128) nt[t] = small[264 + t];
    __syncthreads();
    int jj = (t & 63) * 2, sl = t >> 6;       // 4 K-slices of 32
    int j = blockIdx.x * 128 + jj;
    float a0 = 0.f, a1 = 0.f;
    if (j < out_n) {
        const float* w = Ws + (size_t)(sl * 32) * out_n + j;
        for (int k = 0; k < 32; ++k) {
            float cv = nt[sl * 32 + k];
            float2 r = *reinterpret_cast<const float2*>(w + (size_t)k * out_n);
            a0 += cv * r.x; a1 += cv * r.y;
        }
    }
    s0[t] = a0; s1[t] = a1; __syncthreads();
    if (t < 64 && j < out_n) {
        out[j]     = s0[t] + s0[t + 64] + s0[t + 128] + s0[t + 192] + bs[j];
        out[j + 1] = s1[t] + s1[t + 64] + s1[t + 128] + s1[t + 192] + bs[j + 1];
    }
}

extern "C" void kernel_launch(void* const* d_in, const int* in_sizes, int n_in,
                              void* d_out, int out_size, void* d_ws, size_t ws_size,
                              hipStream_t stream) {
    const float* features = (const float*)d_in[0];
    const int*   eidx     = (const int*)d_in[1];
    const float* trainOT  = (const float*)d_in[2];
    const float* W1 = (const float*)d_in[3];
    const float* b1 = (const float*)d_in[4];
    const float* W2 = (const float*)d_in[5];
    const float* b2 = (const float*)d_in[6];
    const float* Wq = (const float*)d_in[7];
    const float* bq = (const float*)d_in[8];
    const float* Wk = (const float*)d_in[9];
    const float* bk = (const float*)d_in[10];
    const float* Wv = (const float*)d_in[11];
    const float* bv = (const float*)d_in[12];
    const float* Ws = (const float*)d_in[13];
    const float* bs = (const float*)d_in[14];

    int N = in_sizes[0] / 3;
    int E = in_sizes[1] / 2;
    int NB = (N + 255) >> 8;
    int CS = (E + NCHUNK - 1) / NCHUNK;

    char* ws = (char*)d_ws;
    int*   rpD   = (int*)(ws + O_RPD);
    float* dinv  = (float*)(ws + O_DINV);
    float* small = (float*)(ws + O_SMALL);
    float* y     = (float*)(ws + O_Y);
    float* relw  = (float*)(ws + O_RELW);
    float* rel   = (float*)(ws + O_REL);
    int*   ghD   = (int*)(ws + O_GHD);
    int*   ghS   = (int*)(ws + O_GHS);
    int*   goD   = (int*)(ws + O_GOD);
    int*   goS   = (int*)(ws + O_GOS);
    int*   bsD   = (int*)(ws + O_BSD);
    int*   bsS   = (int*)(ws + O_BSS);
    float* part  = (float*)(ws + O_PART);
    float4* xs4  = (float4*)(ws + O_XS);
    float4* g1   = (float4*)(ws + O_G1);
    unsigned int* srtD = (unsigned int*)(ws + O_SRTD);
    unsigned int* srtS = (unsigned int*)(ws + O_SRTS);
    int*   colD  = (int*)(ws + O_COLD);
    float* out   = (float*)d_out;
    int out_n = out_size - 128;

    k_hist<<<dim3(NCHUNK + 1, 2), 256, 0, stream>>>(eidx, ghD, ghS,
                                                    trainOT, Wq, bq, Wk, bk, W2, b2, small,
                                                    E, CS, NB);
    k_goff<<<dim3(NB, 2), 256, 0, stream>>>(ghD, ghS, goD, goS, bsD, bsS, E, NB);
    k_scatter<<<dim3(NCHUNK, 2), 256, 0, stream>>>(eidx, goD, goS, srtD, srtS, E, CS, NB);
    k_build<<<NB, 256, 0, stream>>>(srtD, bsD, rpD, colD, dinv, features, xs4, N);
    k_y<<<(N + 15) / 16, 256, 0, stream>>>(xs4, rpD, colD, dinv, W1, b1, small, g1, y, N);
    k_dv<<<(N + 15) / 16, 256, 0, stream>>>(y, rpD, colD, dinv, small, relw, rel, N);
    k_zS<<<NB, 256, 0, stream>>>(srtS, bsS, relw, rel, g1, W1, b1, part, N);
    k_reduce_part<<<129, 256, 0, stream>>>(part, NB, small);
    k_tinytail<<<1, 1024, 0, stream>>>(trainOT, W2, b2, Wv, bv, small, out + out_n);
    k_speak<<<(out_n + 127) / 128, 256, 0, stream>>>(Ws, bs, small, out, out_n);
}